// Round 10
// baseline (333.434 us; speedup 1.0000x reference)
//
#include <hip/hip_runtime.h>
#include <stdint.h>

// LSTMCell: B=8192, I=H=1024, fp32 in/out.
// Round 10: convergence — main reverted byte-exact to the R5 read-ahead
// 3-barrier schedule (best healthy measurement: 155.7us main). Anti-phase
// (R9) was neutral-to-negative (161.4us): SIMD wave arbitration already
// interleaves the two resident waves; forced opposite program orders only
// degraded per-path codegen. Schedule-structure class closed at ~156us:
// lockstep(168) / deep-prefetch(167) / read-ahead(156) / 32x32(238) /
// anti-phase(161). Prepass + launch kept from R9.
#define BATCH 8192
#define HD    1024
#define NT    32      // K-tiles of 64: 16 for X*Wx^T + 16 for H*Wh^T
// fallback kernel geometry (unchanged, proven)
#define BM    128
#define BNH   32
#define BK    32

typedef __bf16 bf16;
typedef __bf16 bf16x8  __attribute__((ext_vector_type(8)));
typedef __bf16 bf16x4  __attribute__((ext_vector_type(4)));
typedef __bf16 bf16x16 __attribute__((ext_vector_type(16)));
typedef float  f32x4   __attribute__((ext_vector_type(4)));

__device__ __forceinline__ float sigm(float x) {
    return 1.0f / (1.0f + __expf(-x));
}
__device__ __forceinline__ float tanh_f(float x) {
    return 1.0f - 2.0f / (__expf(2.0f * x) + 1.0f);
}
__device__ __forceinline__ bf16x4 cvt4(float4 v) {
    bf16x4 r;
    r[0] = (bf16)v.x; r[1] = (bf16)v.y; r[2] = (bf16)v.z; r[3] = (bf16)v.w;
    return r;
}
// async global->LDS, 16B/lane; LDS dest = wave-uniform base + lane*16.
__device__ __forceinline__ void async_ld16(const void* g, void* l) {
    __builtin_amdgcn_global_load_lds(
        (const __attribute__((address_space(1))) uint32_t*)g,
        (__attribute__((address_space(3))) uint32_t*)l,
        16, 0, 0);
}

// ---- prepass: fp32 -> bf16 for X, H, Wx, Wh into ws (32B stores) ----------
__global__ __launch_bounds__(256) void cvt_prepass(
    const float4* __restrict__ X, const float4* __restrict__ H,
    const float4* __restrict__ Wx, const float4* __restrict__ Wh,
    bf16x16* __restrict__ ws)
{
    const size_t NX = (size_t)BATCH * HD / 16;
    const size_t NW = (size_t)4 * HD * HD / 16;
    const size_t total = 2 * NX + 2 * NW;
    const size_t stride = (size_t)gridDim.x * blockDim.x;
    for (size_t p = (size_t)blockIdx.x * blockDim.x + threadIdx.x;
         p < total; p += stride) {
        const float4* s; size_t o;
        if (p < NX)                { s = X;  o = p; }
        else if (p < 2 * NX)       { s = H;  o = p - NX; }
        else if (p < 2 * NX + NW)  { s = Wx; o = p - 2 * NX; }
        else                       { s = Wh; o = p - 2 * NX - NW; }
        const float4 v0 = s[4 * o + 0], v1 = s[4 * o + 1];
        const float4 v2 = s[4 * o + 2], v3 = s[4 * o + 3];
        bf16x16 r;
        r[0]  = (bf16)v0.x; r[1]  = (bf16)v0.y; r[2]  = (bf16)v0.z; r[3]  = (bf16)v0.w;
        r[4]  = (bf16)v1.x; r[5]  = (bf16)v1.y; r[6]  = (bf16)v1.z; r[7]  = (bf16)v1.w;
        r[8]  = (bf16)v2.x; r[9]  = (bf16)v2.y; r[10] = (bf16)v2.z; r[11] = (bf16)v2.w;
        r[12] = (bf16)v3.x; r[13] = (bf16)v3.y; r[14] = (bf16)v3.z; r[15] = (bf16)v3.w;
        ws[p] = r;
    }
}

// ---- main: 256x256 tile, BK=64, 8 waves, read-ahead 3-barrier (R5) --------
// N=256 cols = 4 gates x 64 h, gate-interleaved: LDS B row r -> weight row
// n = ((r>>4)&3)*1024 + h0 + (r>>6)*16 + (r&15). Wave (wm,wn): 128x64.
// LDS 128KB static, XOR-swizzled (slot ^= row&7) via pre-swizzled global
// source. Staging: prologue A(0),B(0),B(1),A(1)lo; per tile A(t+1)hi early,
// B(t+2)lo / B(t+2)hi+A(t+2)lo late; one vmcnt(6)/tile. Barriers/tile:
//   #1: all waves consumed B(t) (bF01@Q00, bF23@Q02) -> STAGE_B(t+2,0) ok
//   #2: all waves consumed A-lo(t) (aQ@Q42) -> STAGE_A(t+2,0)/B-hi ok
//   #3: after vmcnt(6) -> buf(t+1) visible to trailing reads
// Read issue: bF23(t) before Q00; aF<-im4-7 after Q02; aF01/bF01(t+1)
// after Q40 (each after the last consumer of the regs it overwrites).

#define BAR() __builtin_amdgcn_s_barrier()

#define STAGE_A(tn_, hf_, o0_, o1_) do {                                    \
    const char* s_ = ((tn_) < 16) ? XbC : HbC;                              \
    const int kt_ = ((tn_) & 15) << 7;                                      \
    char* d_ = lds + (((tn_) & 1) << 16) + (hf_) * 16384 + tid16;           \
    async_ld16(s_ + (o0_) + kt_, d_);                                       \
    async_ld16(s_ + (o1_) + kt_, d_ + 8192); } while (0)

#define STAGE_B(tn_, hf_, o0_, o1_) do {                                    \
    const char* s_ = ((tn_) < 16) ? WxC : WhC;                              \
    const int kt_ = ((tn_) & 15) << 7;                                      \
    char* d_ = lds + (((tn_) & 1) << 16) + 32768 + (hf_) * 16384 + tid16;   \
    async_ld16(s_ + (o0_) + kt_, d_);                                       \
    async_ld16(s_ + (o1_) + kt_, d_ + 8192); } while (0)

#define MFMA_Q(IMB_, INB_)                                                  \
    _Pragma("unroll")                                                       \
    for (int im_ = 0; im_ < 4; ++im_) {                                     \
        _Pragma("unroll")                                                   \
        for (int in_ = 0; in_ < 2; ++in_) {                                 \
            acc[im_ + IMB_][in_ + INB_] =                                   \
                __builtin_amdgcn_mfma_f32_16x16x32_bf16(aF[im_][0],         \
                    bF[in_ + INB_][0], acc[im_ + IMB_][in_ + INB_], 0,0,0); \
            acc[im_ + IMB_][in_ + INB_] =                                   \
                __builtin_amdgcn_mfma_f32_16x16x32_bf16(aF[im_][1],         \
                    bF[in_ + INB_][1], acc[im_ + IMB_][in_ + INB_], 0,0,0); \
        }                                                                   \
    }

__global__ __launch_bounds__(512, 2) void lstm_mfma8(
    const bf16* __restrict__ Xb, const bf16* __restrict__ Hb,
    const bf16* __restrict__ Wxb, const bf16* __restrict__ Whb,
    const float* __restrict__ C, const float* __restrict__ bx,
    const float* __restrict__ bh, float* __restrict__ out)
{
    __shared__ __align__(16) char lds[131072];

    const int tid  = threadIdx.x;
    const int lane = tid & 63;
    const int w    = tid >> 6;
    const int wm   = w >> 2;            // M half 0/1
    const int wn   = w & 3;             // N quarter 0..3
    const int quad = lane >> 4;
    const int c16  = lane & 15;

    // XCD k owns M-tiles {4k..4k+3} x all 16 N-cols (N-minor), bijective.
    // Note: blocks bid and bid+256 (the two sequential blocks per CU) share
    // the same M-tile -> A panel stays L2-resident across both.
    const int bid = blockIdx.x;
    const int k8  = bid & 7;
    const int j   = bid >> 3;
    const int mi  = (k8 << 2) | (j & 3);
    const int col = j >> 2;
    const int m0  = mi << 8;
    const int h0  = col << 6;

    // ---- staging addresses (pre-swizzled global source, linear LDS dest) --
    const int tid16 = tid << 4;
    const int R0    = tid >> 3;
    const uint32_t swc = ((tid & 7) ^ (R0 & 7)) << 4;
    const char* XbC = (const char*)Xb;
    const char* HbC = (const char*)Hb;
    const char* WxC = (const char*)Wxb;
    const char* WhC = (const char*)Whb;
    const uint32_t a00 = ((uint32_t)(m0 + R0)       << 11) + swc;
    const uint32_t a01 = ((uint32_t)(m0 + R0 +  64) << 11) + swc;
    const uint32_t a10 = ((uint32_t)(m0 + R0 + 128) << 11) + swc;
    const uint32_t a11 = ((uint32_t)(m0 + R0 + 192) << 11) + swc;
#define NROW(r_) (((((r_) >> 4) & 3) << 10) + h0 + (((r_) >> 6) << 4) + ((r_) & 15))
    const uint32_t b00 = ((uint32_t)NROW(R0)       << 11) + swc;
    const uint32_t b01 = ((uint32_t)NROW(R0 +  64) << 11) + swc;
    const uint32_t b10 = ((uint32_t)NROW(R0 + 128) << 11) + swc;
    const uint32_t b11 = ((uint32_t)NROW(R0 + 192) << 11) + swc;
#undef NROW

    // ---- ds_read bases (swizzled col16: row&7 == c16&7 for all frags) -----
    const int baseA = (wm * 128 + c16) * 128;
    const int baseB = 32768 + (wn * 64 + c16) * 128;
    const int sw0 = ((quad    ) ^ (c16 & 7)) << 4;
    const int sw1 = ((quad + 4) ^ (c16 & 7)) << 4;

    f32x4 acc[8][4];
#pragma unroll
    for (int i = 0; i < 8; ++i)
#pragma unroll
        for (int j2 = 0; j2 < 4; ++j2) acc[i][j2] = (f32x4){0.f, 0.f, 0.f, 0.f};

    // ---- prologue: A(0), B(0), B(1), A(1)-lo; drain tile0, leave 6 --------
    STAGE_A(0, 0, a00, a01);
    STAGE_A(0, 1, a10, a11);
    STAGE_B(0, 0, b00, b01);
    STAGE_B(0, 1, b10, b11);
    STAGE_B(1, 0, b00, b01);
    STAGE_B(1, 1, b10, b11);
    STAGE_A(1, 0, a00, a01);
    asm volatile("s_waitcnt vmcnt(6)" ::: "memory");
    BAR();

    bf16x8 aF[4][2], bF[4][2];
    // initial read of tile-0 first-quad fragments (aF=im0-3, bF01)
    {
        const char* LA = lds + baseA;
        const char* LB = lds + baseB;
#pragma unroll
        for (int im = 0; im < 4; ++im) {
            aF[im][0] = *(const bf16x8*)(LA + im * 2048 + sw0);
            aF[im][1] = *(const bf16x8*)(LA + im * 2048 + sw1);
        }
#pragma unroll
        for (int in = 0; in < 2; ++in) {
            bF[in][0] = *(const bf16x8*)(LB + in * 2048 + sw0);
            bF[in][1] = *(const bf16x8*)(LB + in * 2048 + sw1);
        }
    }

#pragma unroll 1
    for (int t = 0; t < NT; ++t) {
        const char* LA  = lds + ((t & 1) << 16) + baseA;
        const char* LB  = lds + ((t & 1) << 16) + baseB;
        const char* LAn = lds + (((t + 1) & 1) << 16) + baseA;
        const char* LBn = lds + (((t + 1) & 1) << 16) + baseB;

        // stage A-hi(t+1); issue bF23(t) (hidden under Q00)
        if (t + 1 < NT) STAGE_A(t + 1, 1, a10, a11);
#pragma unroll
        for (int in = 2; in < 4; ++in) {
            bF[in][0] = *(const bf16x8*)(LB + in * 2048 + sw0);
            bF[in][1] = *(const bf16x8*)(LB + in * 2048 + sw1);
        }
        __builtin_amdgcn_s_setprio(1);
        MFMA_Q(0, 0);
        __builtin_amdgcn_s_setprio(0);
        __builtin_amdgcn_s_setprio(1);
        MFMA_Q(0, 2);
        __builtin_amdgcn_s_setprio(0);
        // issue aF<-im4-7 (after last use of im0-3)
#pragma unroll
        for (int im = 0; im < 4; ++im) {
            aF[im][0] = *(const bf16x8*)(LA + (im + 4) * 2048 + sw0);
            aF[im][1] = *(const bf16x8*)(LA + (im + 4) * 2048 + sw1);
        }
        BAR();  // #1: all waves consumed B(t) -> B-lo(t+2) stage safe
        if (t + 2 < NT) STAGE_B(t + 2, 0, b00, b01);
        __builtin_amdgcn_s_setprio(1);
        MFMA_Q(4, 2);
        __builtin_amdgcn_s_setprio(0);
        BAR();  // #2: all waves consumed A-lo(t)/B-hi(t) -> stages safe
        if (t + 2 < NT) {
            STAGE_B(t + 2, 1, b10, b11);
            STAGE_A(t + 2, 0, a00, a01);
            asm volatile("s_waitcnt vmcnt(6)" ::: "memory");
        } else if (t == NT - 2) {
            asm volatile("s_waitcnt vmcnt(0)" ::: "memory");
        }
        BAR();  // #3: buf(t+1) visible to all waves
        __builtin_amdgcn_s_setprio(1);
        MFMA_Q(4, 0);
        __builtin_amdgcn_s_setprio(0);
        // trailing reads: next tile's aF01/bF01 (after Q40's last use)
        if (t + 1 < NT) {
#pragma unroll
            for (int im = 0; im < 4; ++im) {
                aF[im][0] = *(const bf16x8*)(LAn + im * 2048 + sw0);
                aF[im][1] = *(const bf16x8*)(LAn + im * 2048 + sw1);
            }
#pragma unroll
            for (int in = 0; in < 2; ++in) {
                bF[in][0] = *(const bf16x8*)(LBn + in * 2048 + sw0);
                bF[in][1] = *(const bf16x8*)(LBn + in * 2048 + sw1);
            }
        }
    }

    // ---- fused LSTM epilogue: lane holds all 4 gates of (m-range, h) ------
    const int h = h0 + wn * 16 + c16;
    float bias[4];
#pragma unroll
    for (int g = 0; g < 4; ++g) bias[g] = bx[g * HD + h] + bh[g * HD + h];
    const size_t BH = (size_t)BATCH * HD;
    const int mb = m0 + wm * 128 + quad * 4;
#pragma unroll
    for (int im = 0; im < 8; ++im) {
#pragma unroll
        for (int r = 0; r < 4; ++r) {
            const int m = mb + im * 16 + r;
            const float gi = acc[im][0][r] + bias[0];
            const float gf = acc[im][1][r] + bias[1];
            const float gg = acc[im][2][r] + bias[2];
            const float go = acc[im][3][r] + bias[3];
            const float ia = sigm(gi);
            const float fa = sigm(gf);
            const float ga = tanh_f(gg);
            const float oa = sigm(go);
            const size_t idx = (size_t)m * HD + h;
            const float nc = fmaf(fa, C[idx], ia * ga);
            const float nh = oa * tanh_f(nc);
            out[idx]          = nh;
            out[BH + idx]     = nh;
            out[2 * BH + idx] = nc;
        }
    }
}

// ---- fallback (proven): fp32 loads + in-loop cvt, register staging --------
__global__ __launch_bounds__(256) void lstm_fused_f32(
    const float* __restrict__ X, const float* __restrict__ Hs,
    const float* __restrict__ C, const float* __restrict__ Wx,
    const float* __restrict__ Wh, const float* __restrict__ bx,
    const float* __restrict__ bh, float* __restrict__ out)
{
    __shared__ __align__(16) bf16 As[BM * BK];
    __shared__ __align__(16) bf16 Bs[BM * BK];
    const int tid = threadIdx.x, lane = tid & 63, w = tid >> 6;
    const int m0 = blockIdx.x * BM, h0 = blockIdx.y * BNH;
    f32x4 acc[2][8];
#pragma unroll
    for (int i = 0; i < 2; ++i)
#pragma unroll
        for (int j = 0; j < 8; ++j) acc[i][j] = (f32x4){0.f, 0.f, 0.f, 0.f};
    int arow[4], col4[4], bn[4];
#pragma unroll
    for (int j = 0; j < 4; ++j) {
        const int off = tid * 16 + j * 4096;
        arow[j] = off >> 7;
        col4[j] = (off & 127) >> 2;
        bn[j]   = ((arow[j] >> 5) << 10) + h0 + (arow[j] & 31);
    }
    const int quad = lane >> 4, c16 = lane & 15;
    float4 pA[4], pB[4];
    auto loadi = [&](int i) {
        const float* Ab = (i < 32) ? X : Hs;
        const float* Wb = (i < 32) ? Wx : Wh;
        const int kin = (i & 31) << 5;
#pragma unroll
        for (int j = 0; j < 4; ++j) {
            pA[j] = *(const float4*)(Ab + (size_t)(m0 + arow[j]) * HD + kin + col4[j]);
            pB[j] = *(const float4*)(Wb + (size_t)bn[j] * HD + kin + col4[j]);
        }
    };
    loadi(0);
#pragma unroll 1
    for (int i = 0; i < 64; ++i) {
        __syncthreads();
#pragma unroll
        for (int j = 0; j < 4; ++j) {
            *(bf16x4*)&As[arow[j] * BK + col4[j]] = cvt4(pA[j]);
            *(bf16x4*)&Bs[arow[j] * BK + col4[j]] = cvt4(pB[j]);
        }
        __syncthreads();
        if (i < 63) loadi(i + 1);
        bf16x8 a[2], b[8];
#pragma unroll
        for (int im = 0; im < 2; ++im)
            a[im] = *(const bf16x8*)((const char*)As + (w * 32 + im * 16 + c16) * 64 + quad * 16);
#pragma unroll
        for (int in = 0; in < 8; ++in)
            b[in] = *(const bf16x8*)((const char*)Bs + (in * 16 + c16) * 64 + quad * 16);
#pragma unroll
        for (int im = 0; im < 2; ++im)
#pragma unroll
            for (int in = 0; in < 8; ++in)
                acc[im][in] = __builtin_amdgcn_mfma_f32_16x16x32_bf16(
                    a[im], b[in], acc[im][in], 0, 0, 0);
    }
    float bias[2][4];
#pragma unroll
    for (int hs = 0; hs < 2; ++hs) {
        const int h = h0 + hs * 16 + c16;
#pragma unroll
        for (int g = 0; g < 4; ++g) bias[hs][g] = bx[g * HD + h] + bh[g * HD + h];
    }
    const size_t BH = (size_t)BATCH * HD;
#pragma unroll
    for (int im = 0; im < 2; ++im)
#pragma unroll
        for (int r = 0; r < 4; ++r) {
            const int m = m0 + w * 32 + im * 16 + quad * 4 + r;
#pragma unroll
            for (int hs = 0; hs < 2; ++hs) {
                const int h = h0 + hs * 16 + c16;
                const float gi = acc[im][hs + 0][r] + bias[hs][0];
                const float gf = acc[im][hs + 2][r] + bias[hs][1];
                const float gg = acc[im][hs + 4][r] + bias[hs][2];
                const float go = acc[im][hs + 6][r] + bias[hs][3];
                const float ia = sigm(gi), fa = sigm(gf);
                const float ga = tanh_f(gg), oa = sigm(go);
                const size_t idx = (size_t)m * HD + h;
                const float nc = fa * C[idx] + ia * ga;
                const float nh = oa * tanh_f(nc);
                out[idx] = nh; out[BH + idx] = nh; out[2 * BH + idx] = nc;
            }
        }
}

extern "C" void kernel_launch(void* const* d_in, const int* in_sizes, int n_in,
                              void* d_out, int out_size, void* d_ws, size_t ws_size,
                              hipStream_t stream) {
    const float* X  = (const float*)d_in[0];
    const float* Hs = (const float*)d_in[1];
    const float* C  = (const float*)d_in[2];
    const float* Wx = (const float*)d_in[3];
    const float* Wh = (const float*)d_in[4];
    const float* bx = (const float*)d_in[5];
    const float* bh = (const float*)d_in[6];
    float* out = (float*)d_out;

    const size_t need = 48ull << 20;  // Xb+Hb (32MB) + Wxb+Whb (16MB)
    if (ws_size >= need) {
        bf16* Xb  = (bf16*)d_ws;
        bf16* Hb  = Xb + (size_t)BATCH * HD;
        bf16* Wxb = Hb + (size_t)BATCH * HD;
        bf16* Whb = Wxb + (size_t)4 * HD * HD;
        cvt_prepass<<<4096, 256, 0, stream>>>(
            (const float4*)X, (const float4*)Hs,
            (const float4*)Wx, (const float4*)Wh, (bf16x16*)d_ws);
        lstm_mfma8<<<dim3(512), dim3(512), 0, stream>>>(
            Xb, Hb, Wxb, Whb, C, bx, bh, out);
    } else {
        dim3 grid(BATCH / BM, HD / BNH);
        lstm_fused_f32<<<grid, 256, 0, stream>>>(X, Hs, C, Wx, Wh, bx, bh, out);
    }
}